// Round 2
// baseline (301.370 us; speedup 1.0000x reference)
//
#include <hip/hip_runtime.h>
#include <hip/hip_bf16.h>

// AdaptiveGraphNetwork: B=4096 batches, N=64 nodes (chain), D=32 feat, H=64 hidden.
// All global tensors are FLOAT32 (per reference). Intermediates staged in LDS
// (bf16 where precision budget allows; 2% relative threshold).
//
// Key refactor: layer-1 of the edge MLP distributes over the concat:
//   hidden[e] = P[dst(e)] + Q[src(e)] + bm1,  P = x@Wm1[0:32], Q = x@Wm1[32:64]
// -> per-node GEMMs instead of per-edge (2x fewer FLOPs in layer 1).

#define NJ 64
#define DD 32
#define HH 64
#define NE 126  // 2*(NJ-1)

__device__ __forceinline__ float bf2f(__hip_bfloat16 h) { return __bfloat162float(h); }

__global__ __launch_bounds__(256, 2)
void agn_kernel(const float* __restrict__ x,    // [B,64,32]
                const float* __restrict__ Wm1,  // [64,64]
                const float* __restrict__ bm1,  // [64]
                const float* __restrict__ Wm2,  // [64,32]
                const float* __restrict__ bm2,  // [32]
                const float* __restrict__ Wu1,  // [64,64]
                const float* __restrict__ bu1,  // [64]
                const float* __restrict__ Wu2,  // [64,32]
                const float* __restrict__ bu2,  // [32]
                const float* __restrict__ rw_p, // [1]
                float* __restrict__ out)        // [B,64,32]
{
    // ---- LDS layout (49152 B -> 3 WG/CU at 160 KiB/CU) ----
    // [0,8192)      xs   : f32  [64][32]          (live whole kernel)
    // [8192,24576)  PQ   : bf16 [64][128]         (phase1 -> phase2a)
    //   [8192,16384)  msgs : f32 [64][32]  ALIAS  (phase2.5 -> phase3)
    // [24576,40960) hbuf : bf16 [128][64]         (phase2a -> phase2b)
    //               hu   : bf16 [64][64]   ALIAS  (phase3  -> phase4)
    // [40960,49152) msgb : bf16 [128][32]         (phase2b -> phase2.5)
    __shared__ __align__(16) char smem[49152];
    float          (*xs)[DD]     = reinterpret_cast<float(*)[DD]>(smem);
    __hip_bfloat16 (*PQ)[2 * HH] = reinterpret_cast<__hip_bfloat16(*)[2 * HH]>(smem + 8192);
    float          (*msgs)[DD]   = reinterpret_cast<float(*)[DD]>(smem + 8192);
    __hip_bfloat16 (*hbuf)[HH]   = reinterpret_cast<__hip_bfloat16(*)[HH]>(smem + 24576);
    __hip_bfloat16 (*hu)[HH]     = reinterpret_cast<__hip_bfloat16(*)[HH]>(smem + 24576);
    __hip_bfloat16 (*msgb)[DD]   = reinterpret_cast<__hip_bfloat16(*)[DD]>(smem + 40960);

    const int b = blockIdx.x;
    const int t = threadIdx.x;
    const int j  = t & 63;   // column for H-wide phases (1,2a,3)
    const int g4 = t >> 6;   // 0..3
    const int d  = t & 31;   // column for D-wide phases (2b,2.5,4)
    const int g8 = t >> 5;   // 0..7

    // ---- load x tile: 2048 f32 = 512 float4, 2 per thread ----
    {
        const float4* xg = reinterpret_cast<const float4*>(x + (size_t)b * NJ * DD);
        float4* xsf = reinterpret_cast<float4*>(&xs[0][0]);
#pragma unroll
        for (int c = 0; c < 2; ++c) {
            int idx = t + c * 256;
            xsf[idx] = xg[idx];
        }
    }

    // ---- phase 1 weights: column j of Wm1 halves (coalesced across lanes) ----
    float wP[32], wQ[32];
#pragma unroll
    for (int k = 0; k < 32; ++k) {
        wP[k] = Wm1[k * HH + j];
        wQ[k] = Wm1[(32 + k) * HH + j];
    }
    __syncthreads();

    // ---- phase 1: P = x@Wm1_top, Q = x@Wm1_bot -> PQ (bf16) ----
    for (int r = 0; r < 16; ++r) {
        const int i = g4 + (r << 2);          // wave-uniform row
        const float4* xrow = reinterpret_cast<const float4*>(&xs[i][0]);
        float aP = 0.f, aQ = 0.f;
#pragma unroll
        for (int k4 = 0; k4 < 8; ++k4) {
            float4 v = xrow[k4];
            aP += v.x * wP[4*k4+0] + v.y * wP[4*k4+1] + v.z * wP[4*k4+2] + v.w * wP[4*k4+3];
            aQ += v.x * wQ[4*k4+0] + v.y * wQ[4*k4+1] + v.z * wQ[4*k4+2] + v.w * wQ[4*k4+3];
        }
        PQ[i][j]      = __float2bfloat16(aP);
        PQ[i][HH + j] = __float2bfloat16(aQ);
    }
    __syncthreads();

    // ---- phase 2a: h[e][j] = relu(P[dst][j] + Q[src][j] + bm1[j]) ----
    {
        const float bm1j = bm1[j];
        for (int r = 0; r < 32; ++r) {
            const int e = g4 + (r << 2);      // 0..127
            if (e < NE) {
                const int dst  = (e < 63) ? e     : e - 62;
                const int srcn = (e < 63) ? e + 1 : e - 63;
                const float hv = bf2f(PQ[dst][j]) + bf2f(PQ[srcn][HH + j]) + bm1j;
                hbuf[e][j] = __float2bfloat16(fmaxf(hv, 0.f));
            }
        }
    }
    __syncthreads();

    // ---- phase 2b: msg[e][d] = relu(h[e] . Wm2[:,d] + bm2[d]) ----
    {
        float wm2c[64];
#pragma unroll
        for (int k = 0; k < 64; ++k) wm2c[k] = Wm2[k * DD + d];
        const float bm2d = bm2[d];
        for (int r = 0; r < 16; ++r) {
            const int e = g8 + (r << 3);      // 0..127
            if (e < NE) {
                const uint4* hrow = reinterpret_cast<const uint4*>(&hbuf[e][0]);
                float acc = 0.f;
#pragma unroll
                for (int q = 0; q < 8; ++q) {
                    uint4 u = hrow[q];
                    acc += __uint_as_float(u.x << 16)          * wm2c[8*q+0]
                         + __uint_as_float(u.x & 0xFFFF0000u)  * wm2c[8*q+1]
                         + __uint_as_float(u.y << 16)          * wm2c[8*q+2]
                         + __uint_as_float(u.y & 0xFFFF0000u)  * wm2c[8*q+3]
                         + __uint_as_float(u.z << 16)          * wm2c[8*q+4]
                         + __uint_as_float(u.z & 0xFFFF0000u)  * wm2c[8*q+5]
                         + __uint_as_float(u.w << 16)          * wm2c[8*q+6]
                         + __uint_as_float(u.w & 0xFFFF0000u)  * wm2c[8*q+7];
                }
                msgb[e][d] = __float2bfloat16(fmaxf(acc + bm2d, 0.f));
            }
        }
    }
    __syncthreads();

    // ---- phase 2.5: chain scatter-add -> msgs (f32, aliases dead PQ) ----
    // messages[i] = (i<63 ? msg[i] : 0) + (i>0 ? msg[62+i] : 0)
    for (int r = 0; r < 8; ++r) {
        const int i = g8 + (r << 3);          // 0..63
        float m = 0.f;
        if (i < 63) m += bf2f(msgb[i][d]);
        if (i > 0)  m += bf2f(msgb[62 + i][d]);
        msgs[i][d] = m;
    }
    __syncthreads();

    // ---- phase 3: hu[i][j] = relu(x[i].Wu1_top[:,j] + messages[i].Wu1_bot[:,j] + bu1[j]) ----
    {
        float wU[64];
#pragma unroll
        for (int k = 0; k < 64; ++k) wU[k] = Wu1[k * HH + j];
        const float bu1j = bu1[j];
        for (int r = 0; r < 16; ++r) {
            const int i = g4 + (r << 2);
            const float4* xrow = reinterpret_cast<const float4*>(&xs[i][0]);
            const float4* mrow = reinterpret_cast<const float4*>(&msgs[i][0]);
            float acc = bu1j;
#pragma unroll
            for (int k4 = 0; k4 < 8; ++k4) {
                float4 v = xrow[k4];
                acc += v.x * wU[4*k4+0] + v.y * wU[4*k4+1] + v.z * wU[4*k4+2] + v.w * wU[4*k4+3];
            }
#pragma unroll
            for (int k4 = 0; k4 < 8; ++k4) {
                float4 v = mrow[k4];
                acc += v.x * wU[32+4*k4+0] + v.y * wU[32+4*k4+1] + v.z * wU[32+4*k4+2] + v.w * wU[32+4*k4+3];
            }
            hu[i][j] = __float2bfloat16(fmaxf(acc, 0.f));
        }
    }
    __syncthreads();

    // ---- phase 4: out[i][d] = rw*(hu[i].Wu2[:,d] + bu2[d]) + (1-rw)*x[i][d] ----
    {
        float wu2c[64];
#pragma unroll
        for (int k = 0; k < 64; ++k) wu2c[k] = Wu2[k * DD + d];
        const float bu2d = bu2[d];
        const float rw = rw_p[0];
        const float om = 1.f - rw;
        float* og = out + (size_t)b * NJ * DD;
        for (int r = 0; r < 8; ++r) {
            const int i = g8 + (r << 3);
            const uint4* hrow = reinterpret_cast<const uint4*>(&hu[i][0]);
            float acc = bu2d;
#pragma unroll
            for (int q = 0; q < 8; ++q) {
                uint4 u = hrow[q];
                acc += __uint_as_float(u.x << 16)          * wu2c[8*q+0]
                     + __uint_as_float(u.x & 0xFFFF0000u)  * wu2c[8*q+1]
                     + __uint_as_float(u.y << 16)          * wu2c[8*q+2]
                     + __uint_as_float(u.y & 0xFFFF0000u)  * wu2c[8*q+3]
                     + __uint_as_float(u.z << 16)          * wu2c[8*q+4]
                     + __uint_as_float(u.z & 0xFFFF0000u)  * wu2c[8*q+5]
                     + __uint_as_float(u.w << 16)          * wu2c[8*q+6]
                     + __uint_as_float(u.w & 0xFFFF0000u)  * wu2c[8*q+7];
            }
            og[i * DD + d] = rw * acc + om * xs[i][d];
        }
    }
}

extern "C" void kernel_launch(void* const* d_in, const int* in_sizes, int n_in,
                              void* d_out, int out_size, void* d_ws, size_t ws_size,
                              hipStream_t stream) {
    const float* x   = (const float*)d_in[0];
    const float* Wm1 = (const float*)d_in[1];
    const float* bm1 = (const float*)d_in[2];
    const float* Wm2 = (const float*)d_in[3];
    const float* bm2 = (const float*)d_in[4];
    const float* Wu1 = (const float*)d_in[5];
    const float* bu1 = (const float*)d_in[6];
    const float* Wu2 = (const float*)d_in[7];
    const float* bu2 = (const float*)d_in[8];
    const float* rw  = (const float*)d_in[9];
    float* out = (float*)d_out;

    const int B = in_sizes[0] / (NJ * DD);
    agn_kernel<<<B, 256, 0, stream>>>(x, Wm1, bm1, Wm2, bm2, Wu1, bu1, Wu2, bu2, rw, out);
}

// Round 3
// 125.162 us; speedup vs baseline: 2.4078x; 2.4078x over previous
//
#include <hip/hip_runtime.h>
#include <hip/hip_bf16.h>

// AdaptiveGraphNetwork via MFMA (16x16x32 bf16), B=4096, N=64, D=32, H=64.
// Per WG: NB=2 batches. Phases:
//  1: PQ[128][128] = x[128][32] @ [Wm1_top | Wm1_bot]      (64 MFMA)
//  2: msgb[256][32] = relu(gather(PQ)+bm1) @ Wm2 + bm2,relu (64 MFMA)
//  3: hu[128][64] = relu([x | scatter(msgb)] @ Wu1 + bu1)   (64 MFMA)
//  4: out = rw*(hu @ Wu2 + bu2) + (1-rw)*x                  (32 MFMA)
// Fragment maps (m89/m91-verified): A[m=lane&15][k=quad*8+j],
// B[k=quad*8+j][n=lane&15], C/D[row=quad*4+reg][col=lane&15].
// LDS strides 272/80/144 B: ==16 mod 32 (conflict-free-ish) and 16B-aligned.

typedef __bf16 bf16x8 __attribute__((ext_vector_type(8)));
typedef float  f32x4  __attribute__((ext_vector_type(4)));

#define NB 2
#define ROWS  (NB * 64)    // 128 node rows per WG
#define EROWS (NB * 128)   // 256 padded edge rows per WG
#define PQ_S 136           // ushort stride (272 B)
#define MB_S 40            // 80 B
#define HU_S 72            // 144 B

typedef unsigned short u16;

__device__ __forceinline__ u16 f2b(float f) {
    return __builtin_bit_cast(u16, (__bf16)f);
}
__device__ __forceinline__ f32x4 MFMA(bf16x8 a, bf16x8 b, f32x4 c) {
    return __builtin_amdgcn_mfma_f32_16x16x32_bf16(a, b, c, 0, 0, 0);
}

__global__ __launch_bounds__(256, 2)
void agn_mfma(const float* __restrict__ x, const float* __restrict__ Wm1,
              const float* __restrict__ bm1, const float* __restrict__ Wm2,
              const float* __restrict__ bm2, const float* __restrict__ Wu1,
              const float* __restrict__ bu1, const float* __restrict__ Wu2,
              const float* __restrict__ bu2, const float* __restrict__ rw_p,
              float* __restrict__ out)
{
    __shared__ __align__(16) u16 sPQ[ROWS * PQ_S];   // 34816 B (aliased by sHU)
    __shared__ __align__(16) u16 sMB[EROWS * MB_S];  // 20480 B
    u16* sHU = sPQ;                                  // 128*144B = 18432 <= 34816

    const int t = threadIdx.x;
    const int w = t >> 6;         // wave 0..3
    const int lane = t & 63;
    const int ln = lane & 15;
    const int q  = lane >> 4;     // quad 0..3

    const size_t blk = (size_t)blockIdx.x * (NB * 64 * 32);
    const float* xb = x + blk;
    float*       ob = out + blk;

    // ================= Phase 1: PQ = x @ [Wm1_top | Wm1_bot] =================
    bf16x8 B1[8];
#pragma unroll
    for (int nt = 0; nt < 8; ++nt) {
        const int koff = (nt < 4) ? 0 : 32;
        const int wcol = (nt & 3) * 16 + ln;
#pragma unroll
        for (int j = 0; j < 8; ++j)
            B1[nt][j] = (__bf16)Wm1[(koff + q * 8 + j) * 64 + wcol];
    }
#pragma unroll
    for (int m = 0; m < 2; ++m) {
        const int mt = 2 * w + m;
        const int row = mt * 16 + ln;
        const float* xr = xb + row * 32 + q * 8;
        float4 a0 = *(const float4*)xr;
        float4 a1 = *(const float4*)(xr + 4);
        bf16x8 A = {(__bf16)a0.x, (__bf16)a0.y, (__bf16)a0.z, (__bf16)a0.w,
                    (__bf16)a1.x, (__bf16)a1.y, (__bf16)a1.z, (__bf16)a1.w};
#pragma unroll
        for (int nt = 0; nt < 8; ++nt) {
            f32x4 acc = {0.f, 0.f, 0.f, 0.f};
            acc = MFMA(A, B1[nt], acc);
            const int crow = mt * 16 + q * 4;
            const int ccol = nt * 16 + ln;
#pragma unroll
            for (int r = 0; r < 4; ++r)
                sPQ[(crow + r) * PQ_S + ccol] = f2b(acc[r]);
        }
    }

    // --- preload phase-2 weights/biases (global, independent of LDS) ---
    float bm1v[2][8];
    bf16x8 B2[2][2];
#pragma unroll
    for (int s = 0; s < 2; ++s) {
#pragma unroll
        for (int j = 0; j < 8; ++j)
            bm1v[s][j] = bm1[s * 32 + q * 8 + j];
#pragma unroll
        for (int nt = 0; nt < 2; ++nt)
#pragma unroll
            for (int j = 0; j < 8; ++j)
                B2[s][nt][j] = (__bf16)Wm2[(s * 32 + q * 8 + j) * 32 + nt * 16 + ln];
    }
    float bm2v[2] = { bm2[ln], bm2[16 + ln] };
    __syncthreads();

    // ========== Phase 2: msgb = relu( relu(gather(PQ)+bm1) @ Wm2 + bm2 ) =====
#pragma unroll
    for (int m = 0; m < 4; ++m) {
        const int mt = 4 * w + m;
        const int erow = mt * 16 + ln;
        const int bb = erow >> 7;
        int e = erow & 127;
        if (e >= 126) e = 0;                       // pad rows: compute garbage, never read
        const int dst  = (e < 63) ? e : e - 62;
        const int srcn = (e < 63) ? e + 1 : e - 63;
        const int pd = (bb << 6) + dst;
        const int ps = (bb << 6) + srcn;
        bf16x8 A2[2];
#pragma unroll
        for (int s = 0; s < 2; ++s) {
            const int k0 = s * 32 + q * 8;
            uint4 u1 = *(const uint4*)&sPQ[pd * PQ_S + k0];
            uint4 u2 = *(const uint4*)&sPQ[ps * PQ_S + 64 + k0];
            const unsigned* p1 = (const unsigned*)&u1;
            const unsigned* p2 = (const unsigned*)&u2;
#pragma unroll
            for (int h = 0; h < 4; ++h) {
                float lo = __uint_as_float(p1[h] << 16) +
                           __uint_as_float(p2[h] << 16) + bm1v[s][2 * h];
                float hi = __uint_as_float(p1[h] & 0xFFFF0000u) +
                           __uint_as_float(p2[h] & 0xFFFF0000u) + bm1v[s][2 * h + 1];
                A2[s][2 * h]     = (__bf16)fmaxf(lo, 0.f);
                A2[s][2 * h + 1] = (__bf16)fmaxf(hi, 0.f);
            }
        }
#pragma unroll
        for (int nt = 0; nt < 2; ++nt) {
            f32x4 acc = {0.f, 0.f, 0.f, 0.f};
            acc = MFMA(A2[0], B2[0][nt], acc);
            acc = MFMA(A2[1], B2[1][nt], acc);
            const int crow = mt * 16 + q * 4;
            const int ccol = nt * 16 + ln;
#pragma unroll
            for (int r = 0; r < 4; ++r)
                sMB[(crow + r) * MB_S + ccol] = f2b(fmaxf(acc[r] + bm2v[nt], 0.f));
        }
    }

    // --- preload phase-3 weights/biases ---
    bf16x8 B3[2][4];
#pragma unroll
    for (int s = 0; s < 2; ++s)
#pragma unroll
        for (int nt = 0; nt < 4; ++nt)
#pragma unroll
            for (int j = 0; j < 8; ++j)
                B3[s][nt][j] = (__bf16)Wu1[(s * 32 + q * 8 + j) * 64 + nt * 16 + ln];
    float bu1v[4] = { bu1[ln], bu1[16 + ln], bu1[32 + ln], bu1[48 + ln] };
    __syncthreads();

    // ===== Phase 3: hu = relu([x | scatter(msgb)] @ Wu1 + bu1) ===============
#pragma unroll
    for (int m = 0; m < 2; ++m) {
        const int mt = 2 * w + m;
        const int row = mt * 16 + ln;
        const int bb = row >> 6;
        const int i2 = row & 63;
        const float* xr = xb + row * 32 + q * 8;
        float4 a0 = *(const float4*)xr;
        float4 a1 = *(const float4*)(xr + 4);
        bf16x8 A0 = {(__bf16)a0.x, (__bf16)a0.y, (__bf16)a0.z, (__bf16)a0.w,
                     (__bf16)a1.x, (__bf16)a1.y, (__bf16)a1.z, (__bf16)a1.w};
        float mv[8] = {0.f, 0.f, 0.f, 0.f, 0.f, 0.f, 0.f, 0.f};
        if (i2 < 63) {
            uint4 u = *(const uint4*)&sMB[(bb * 128 + i2) * MB_S + q * 8];
            const unsigned* p = (const unsigned*)&u;
#pragma unroll
            for (int h = 0; h < 4; ++h) {
                mv[2 * h]     += __uint_as_float(p[h] << 16);
                mv[2 * h + 1] += __uint_as_float(p[h] & 0xFFFF0000u);
            }
        }
        if (i2 > 0) {
            uint4 u = *(const uint4*)&sMB[(bb * 128 + 62 + i2) * MB_S + q * 8];
            const unsigned* p = (const unsigned*)&u;
#pragma unroll
            for (int h = 0; h < 4; ++h) {
                mv[2 * h]     += __uint_as_float(p[h] << 16);
                mv[2 * h + 1] += __uint_as_float(p[h] & 0xFFFF0000u);
            }
        }
        bf16x8 A1;
#pragma unroll
        for (int j = 0; j < 8; ++j) A1[j] = (__bf16)mv[j];
#pragma unroll
        for (int nt = 0; nt < 4; ++nt) {
            f32x4 acc = {0.f, 0.f, 0.f, 0.f};
            acc = MFMA(A0, B3[0][nt], acc);
            acc = MFMA(A1, B3[1][nt], acc);
            const int crow = mt * 16 + q * 4;
            const int ccol = nt * 16 + ln;
#pragma unroll
            for (int r = 0; r < 4; ++r)
                sHU[(crow + r) * HU_S + ccol] = f2b(fmaxf(acc[r] + bu1v[nt], 0.f));
        }
    }

    // --- preload phase-4 weights/biases ---
    bf16x8 B4[2][2];
#pragma unroll
    for (int s = 0; s < 2; ++s)
#pragma unroll
        for (int nt = 0; nt < 2; ++nt)
#pragma unroll
            for (int j = 0; j < 8; ++j)
                B4[s][nt][j] = (__bf16)Wu2[(s * 32 + q * 8 + j) * 32 + nt * 16 + ln];
    float bu2v[2] = { bu2[ln], bu2[16 + ln] };
    const float rw = rw_p[0];
    const float omrw = 1.f - rw;
    __syncthreads();

    // ===== Phase 4: out = rw*(hu @ Wu2 + bu2) + (1-rw)*x =====================
#pragma unroll
    for (int m = 0; m < 2; ++m) {
        const int mt = 2 * w + m;
        const int arow = mt * 16 + ln;
        bf16x8 A[2];
#pragma unroll
        for (int s = 0; s < 2; ++s) {
            uint4 u = *(const uint4*)&sHU[arow * HU_S + s * 32 + q * 8];
            A[s] = __builtin_bit_cast(bf16x8, u);
        }
#pragma unroll
        for (int nt = 0; nt < 2; ++nt) {
            f32x4 acc = {0.f, 0.f, 0.f, 0.f};
            acc = MFMA(A[0], B4[0][nt], acc);
            acc = MFMA(A[1], B4[1][nt], acc);
            const int crow = mt * 16 + q * 4;
            const int ccol = nt * 16 + ln;
#pragma unroll
            for (int r = 0; r < 4; ++r) {
                const int off = (crow + r) * 32 + ccol;
                ob[off] = rw * (acc[r] + bu2v[nt]) + omrw * xb[off];
            }
        }
    }
}

extern "C" void kernel_launch(void* const* d_in, const int* in_sizes, int n_in,
                              void* d_out, int out_size, void* d_ws, size_t ws_size,
                              hipStream_t stream) {
    const float* x   = (const float*)d_in[0];
    const float* Wm1 = (const float*)d_in[1];
    const float* bm1 = (const float*)d_in[2];
    const float* Wm2 = (const float*)d_in[3];
    const float* bm2 = (const float*)d_in[4];
    const float* Wu1 = (const float*)d_in[5];
    const float* bu1 = (const float*)d_in[6];
    const float* Wu2 = (const float*)d_in[7];
    const float* bu2 = (const float*)d_in[8];
    const float* rw  = (const float*)d_in[9];
    float* out = (float*)d_out;

    const int B = in_sizes[0] / (64 * 32);
    agn_mfma<<<B / NB, 256, 0, stream>>>(x, Wm1, bm1, Wm2, bm2, Wu1, bu1, Wu2, bu2, rw, out);
}

// Round 4
// 121.679 us; speedup vs baseline: 2.4768x; 1.0286x over previous
//
#include <hip/hip_runtime.h>
#include <hip/hip_bf16.h>

// AdaptiveGraphNetwork via MFMA 16x16x32 bf16. B=4096, N=64, D=32, H=64.
// One WG processes NBATCH=8 batches (loop, NBI=2 per iteration); weight
// fragments are loaded ONCE per WG into registers and reused -> the per-batch
// cost is 4 MFMA phases + 3 LDS round trips.
//
// Phase A (merged edge-gather + layer1): h[e] = relu(x[dst]@Wm1_t + x[src]@Wm1_b + bm1)
//   A-fragments gathered directly from global x (L2-warm), no PQ staging.
// Phase B: msgb = relu(h @ Wm2 + bm2)          (LDS sH -> sMB)
// Phase C: hu = relu([x | scatter(msgb)] @ Wu1 + bu1)
// Phase D: out = rw*(hu @ Wu2 + bu2) + (1-rw)*x
//
// Fragment maps (m89/m91-verified): A[m=lane&15][k=quad*8+j],
// B[k=quad*8+j][n=lane&15], C/D[row=quad*4+reg][col=lane&15].

typedef __bf16 bf16x8 __attribute__((ext_vector_type(8)));
typedef float  f32x4  __attribute__((ext_vector_type(4)));
typedef unsigned short u16;

#define NBATCH 8
#define NBI 2
#define ITERS (NBATCH / NBI)
#define HS  72   // sH row stride in u16 (144 B, 16B-aligned)
#define MBS 40   // sMB row stride in u16 (80 B, 16B-aligned)

__device__ __forceinline__ u16 f2b(float f) { return __builtin_bit_cast(u16, (__bf16)f); }
__device__ __forceinline__ f32x4 MFMA(bf16x8 a, bf16x8 b, f32x4 c) {
    return __builtin_amdgcn_mfma_f32_16x16x32_bf16(a, b, c, 0, 0, 0);
}
__device__ __forceinline__ bf16x8 pack8(float4 a, float4 b) {
    bf16x8 r = {(__bf16)a.x, (__bf16)a.y, (__bf16)a.z, (__bf16)a.w,
                (__bf16)b.x, (__bf16)b.y, (__bf16)b.z, (__bf16)b.w};
    return r;
}

__global__ __launch_bounds__(256, 2)
void agn_mfma(const float* __restrict__ x, const float* __restrict__ Wm1,
              const float* __restrict__ bm1, const float* __restrict__ Wm2,
              const float* __restrict__ bm2, const float* __restrict__ Wu1,
              const float* __restrict__ bu1, const float* __restrict__ Wu2,
              const float* __restrict__ bu2, const float* __restrict__ rw_p,
              float* __restrict__ out)
{
    __shared__ __align__(16) u16 sH[256 * HS];    // 36864 B; rows 0..255 edge-h, aliased rows 0..127 as hu
    __shared__ __align__(16) u16 sMB[256 * MBS];  // 20480 B

    const int t = threadIdx.x;
    const int w = t >> 6;
    const int lane = t & 63;
    const int ln = lane & 15;
    const int q  = lane >> 4;

    // ---------------- weight fragments (once per WG) ----------------
    bf16x8 B1a[4], B1b[4], B2[2][2], B3[2][4], B4[2][2];
#pragma unroll
    for (int nt = 0; nt < 4; ++nt)
#pragma unroll
        for (int j = 0; j < 8; ++j) {
            B1a[nt][j] = (__bf16)Wm1[(q * 8 + j) * 64 + nt * 16 + ln];
            B1b[nt][j] = (__bf16)Wm1[(32 + q * 8 + j) * 64 + nt * 16 + ln];
        }
#pragma unroll
    for (int s = 0; s < 2; ++s)
#pragma unroll
        for (int nt = 0; nt < 2; ++nt)
#pragma unroll
            for (int j = 0; j < 8; ++j)
                B2[s][nt][j] = (__bf16)Wm2[(s * 32 + q * 8 + j) * 32 + nt * 16 + ln];
#pragma unroll
    for (int s = 0; s < 2; ++s)
#pragma unroll
        for (int nt = 0; nt < 4; ++nt)
#pragma unroll
            for (int j = 0; j < 8; ++j)
                B3[s][nt][j] = (__bf16)Wu1[(s * 32 + q * 8 + j) * 64 + nt * 16 + ln];
#pragma unroll
    for (int s = 0; s < 2; ++s)
#pragma unroll
        for (int nt = 0; nt < 2; ++nt)
#pragma unroll
            for (int j = 0; j < 8; ++j)
                B4[s][nt][j] = (__bf16)Wu2[(s * 32 + q * 8 + j) * 32 + nt * 16 + ln];

    float bm1v[4], bu1v[4], bm2v[2], bu2v[2];
#pragma unroll
    for (int nt = 0; nt < 4; ++nt) { bm1v[nt] = bm1[nt * 16 + ln]; bu1v[nt] = bu1[nt * 16 + ln]; }
#pragma unroll
    for (int nt = 0; nt < 2; ++nt) { bm2v[nt] = bm2[nt * 16 + ln]; bu2v[nt] = bu2[nt * 16 + ln]; }
    const float rw = rw_p[0];
    const float om = 1.f - rw;

    const size_t base = (size_t)blockIdx.x * (NBATCH * 64 * 32);

    for (int it = 0; it < ITERS; ++it) {
        const float* xit = x + base + (size_t)it * (NBI * 64 * 32);
        float*       oit = out + base + (size_t)it * (NBI * 64 * 32);

        // ===== Phase A: h[erow] = relu(x[dst]@Wm1_t + x[src]@Wm1_b + bm1) =====
        {
            float4 xd[4][2], xsv[4][2];
#pragma unroll
            for (int m = 0; m < 4; ++m) {
                const int mt = 4 * w + m;
                const int erow = mt * 16 + ln;
                const int bb = erow >> 7;
                int e = erow & 127;
                if (e >= 126) e = 0;  // pad rows, never read
                const int dst  = (e < 63) ? e : e - 62;
                const int srcn = (e < 63) ? e + 1 : e - 63;
                const float* pd = xit + ((bb << 6) + dst) * 32 + q * 8;
                const float* ps = xit + ((bb << 6) + srcn) * 32 + q * 8;
                xd[m][0] = *(const float4*)pd;  xd[m][1] = *(const float4*)(pd + 4);
                xsv[m][0] = *(const float4*)ps; xsv[m][1] = *(const float4*)(ps + 4);
            }
#pragma unroll
            for (int m = 0; m < 4; ++m) {
                const int mt = 4 * w + m;
                bf16x8 Ad = pack8(xd[m][0], xd[m][1]);
                bf16x8 As = pack8(xsv[m][0], xsv[m][1]);
#pragma unroll
                for (int nt = 0; nt < 4; ++nt) {
                    f32x4 acc = {0.f, 0.f, 0.f, 0.f};
                    acc = MFMA(Ad, B1a[nt], acc);
                    acc = MFMA(As, B1b[nt], acc);
                    const int rb = mt * 16 + q * 4;
                    const int c  = nt * 16 + ln;
#pragma unroll
                    for (int r = 0; r < 4; ++r)
                        sH[(rb + r) * HS + c] = f2b(fmaxf(acc[r] + bm1v[nt], 0.f));
                }
            }
        }
        __syncthreads();

        // ===== Phase B: msgb = relu(h @ Wm2 + bm2) =====
#pragma unroll
        for (int m = 0; m < 4; ++m) {
            const int mt = 4 * w + m;
            const int row = mt * 16 + ln;
            bf16x8 A0 = __builtin_bit_cast(bf16x8, *(const uint4*)&sH[row * HS + q * 8]);
            bf16x8 A1 = __builtin_bit_cast(bf16x8, *(const uint4*)&sH[row * HS + 32 + q * 8]);
#pragma unroll
            for (int nt = 0; nt < 2; ++nt) {
                f32x4 acc = {0.f, 0.f, 0.f, 0.f};
                acc = MFMA(A0, B2[0][nt], acc);
                acc = MFMA(A1, B2[1][nt], acc);
                const int rb = mt * 16 + q * 4;
                const int c  = nt * 16 + ln;
#pragma unroll
                for (int r = 0; r < 4; ++r)
                    sMB[(rb + r) * MBS + c] = f2b(fmaxf(acc[r] + bm2v[nt], 0.f));
            }
        }
        __syncthreads();

        // ===== Phase C: hu = relu([x | scatter(msgb)] @ Wu1 + bu1) =====
#pragma unroll
        for (int m = 0; m < 2; ++m) {
            const int mt = 2 * w + m;
            const int row = mt * 16 + ln;   // 0..127 within 2-batch chunk
            const int bb = row >> 6;
            const int i2 = row & 63;
            const float* p = xit + row * 32 + q * 8;
            float4 a0 = *(const float4*)p;
            float4 a1 = *(const float4*)(p + 4);
            bf16x8 A0 = pack8(a0, a1);
            float mv[8] = {0.f, 0.f, 0.f, 0.f, 0.f, 0.f, 0.f, 0.f};
            if (i2 < 63) {
                uint4 u = *(const uint4*)&sMB[((bb << 7) + i2) * MBS + q * 8];
                const unsigned* pu = (const unsigned*)&u;
#pragma unroll
                for (int h = 0; h < 4; ++h) {
                    mv[2 * h]     += __uint_as_float(pu[h] << 16);
                    mv[2 * h + 1] += __uint_as_float(pu[h] & 0xFFFF0000u);
                }
            }
            if (i2 > 0) {
                uint4 u = *(const uint4*)&sMB[((bb << 7) + 62 + i2) * MBS + q * 8];
                const unsigned* pu = (const unsigned*)&u;
#pragma unroll
                for (int h = 0; h < 4; ++h) {
                    mv[2 * h]     += __uint_as_float(pu[h] << 16);
                    mv[2 * h + 1] += __uint_as_float(pu[h] & 0xFFFF0000u);
                }
            }
            bf16x8 A1;
#pragma unroll
            for (int j = 0; j < 8; ++j) A1[j] = (__bf16)mv[j];
#pragma unroll
            for (int nt = 0; nt < 4; ++nt) {
                f32x4 acc = {0.f, 0.f, 0.f, 0.f};
                acc = MFMA(A0, B3[0][nt], acc);
                acc = MFMA(A1, B3[1][nt], acc);
                const int rb = mt * 16 + q * 4;
                const int c  = nt * 16 + ln;
#pragma unroll
                for (int r = 0; r < 4; ++r)
                    sH[(rb + r) * HS + c] = f2b(fmaxf(acc[r] + bu1v[nt], 0.f)); // hu, rows 0..127
            }
        }
        __syncthreads();

        // ===== Phase D: out = rw*(hu @ Wu2 + bu2) + (1-rw)*x =====
#pragma unroll
        for (int m = 0; m < 2; ++m) {
            const int mt = 2 * w + m;
            const int arow = mt * 16 + ln;
            bf16x8 A0 = __builtin_bit_cast(bf16x8, *(const uint4*)&sH[arow * HS + q * 8]);
            bf16x8 A1 = __builtin_bit_cast(bf16x8, *(const uint4*)&sH[arow * HS + 32 + q * 8]);
#pragma unroll
            for (int nt = 0; nt < 2; ++nt) {
                f32x4 acc = {0.f, 0.f, 0.f, 0.f};
                acc = MFMA(A0, B4[0][nt], acc);
                acc = MFMA(A1, B4[1][nt], acc);
                const int rb = mt * 16 + q * 4;
                const int c  = nt * 16 + ln;
#pragma unroll
                for (int r = 0; r < 4; ++r) {
                    const int off = (rb + r) * 32 + c;
                    oit[off] = rw * (acc[r] + bu2v[nt]) + om * xit[off];
                }
            }
        }
        __syncthreads();  // sH (=hu) consumed before next iter's Phase A overwrites
    }
}

extern "C" void kernel_launch(void* const* d_in, const int* in_sizes, int n_in,
                              void* d_out, int out_size, void* d_ws, size_t ws_size,
                              hipStream_t stream) {
    const float* x   = (const float*)d_in[0];
    const float* Wm1 = (const float*)d_in[1];
    const float* bm1 = (const float*)d_in[2];
    const float* Wm2 = (const float*)d_in[3];
    const float* bm2 = (const float*)d_in[4];
    const float* Wu1 = (const float*)d_in[5];
    const float* bu1 = (const float*)d_in[6];
    const float* Wu2 = (const float*)d_in[7];
    const float* bu2 = (const float*)d_in[8];
    const float* rw  = (const float*)d_in[9];
    float* out = (float*)d_out;

    const int B = in_sizes[0] / (64 * 32);
    agn_mfma<<<B / NBATCH, 256, 0, stream>>>(x, Wm1, bm1, Wm2, bm2, Wu1, bu1, Wu2, bu2, rw, out);
}